// Round 1
// 826.833 us; speedup vs baseline: 1.1325x; 1.1325x over previous
//
#include <hip/hip_runtime.h>
#include <math.h>

#define HDIM   7168
#define NEXP   256
#define NGROUP 8
#define EPG    32
#define TOPKG  4
#define TOPK   8
#define RSF    2.5

#define BK     32
#define KHALF  3584
#define NCH    112          // 32-k chunks per K-half
#define NB_REF 512          // refine fast-path token cap

// main path now accumulates plain fp32 (no fp64 drain); error sigma ~5e-7 in
// logit units (~1e-7 in score units). Refine thresholds widened accordingly.
#define TAU    3e-6f
#define TAUG   3e-6f

#define BUFSZ  49152        // per LDS buffer: A hi/lo 16K | B hi 16K | B lo 16K

typedef _Float16 f16x8 __attribute__((ext_vector_type(8)));
typedef float    f32x16 __attribute__((ext_vector_type(16)));

// ws layout (bytes) — unchanged from previous version:
//   0        cnt (int)
//   256      list (16384 int)
//   66048    khi image: 224 chunks x 16384 B   ([c][u(4)][col(256)][8 f16])
//   3736064  klo image: same
//   7406080  fp32 partial logits [kh][T][256] (33.55 MB), ALIASED by refine
#define WS_CNT_OFF   0
#define WS_LIST_OFF  256
#define WS_KHI_OFF   66048
#define WS_KLO_OFF   3736064
#define WS_BUF_OFF   7406080
#define WS_NEED      (7406080ULL + 33554432ULL)

__device__ __forceinline__ void gload_lds16(const void* g, void* l) {
    __builtin_amdgcn_global_load_lds(
        (const __attribute__((address_space(1))) unsigned int*)g,
        (__attribute__((address_space(3))) unsigned int*)(unsigned long long)(uintptr_t)l,
        16, 0, 0);
}

__device__ __forceinline__ void cvt8(float4 a, float4 b, f16x8& h8, f16x8& l8) {
    float f[8] = {a.x, a.y, a.z, a.w, b.x, b.y, b.z, b.w};
#pragma unroll
    for (int i = 0; i < 8; ++i) {
        _Float16 h = (_Float16)f[i];
        h8[i] = h;
        l8[i] = (_Float16)((f[i] - (float)h) * 2048.0f);
    }
}

// ---------------- prep: split + relayout gate matrix, zero counter ----------
__global__ __launch_bounds__(256) void moe_prep(
    const float* __restrict__ wk, char* __restrict__ khi, char* __restrict__ klo,
    int* __restrict__ cnt)
{
    if (blockIdx.x == 0 && threadIdx.x == 0) *cnt = 0;
    const int c   = blockIdx.x;    // global 32-k chunk 0..223
    const int col = threadIdx.x;
    const long cb = (long)c * 16384 + (long)col * 16;
#pragma unroll
    for (int u = 0; u < 4; ++u) {
        f16x8 h8, l8;
#pragma unroll
        for (int h = 0; h < 8; ++h) {
            float v = wk[(long)(c * 32 + u * 8 + h) * NEXP + col];
            _Float16 hi = (_Float16)v;
            h8[h] = hi;
            l8[h] = (_Float16)((v - (float)hi) * 2048.0f);
        }
        *(f16x8*)(khi + cb + u * 4096) = h8;
        *(f16x8*)(klo + cb + u * 4096) = l8;
    }
}

// ---------------- main: split-K split-f16 MFMA GEMM -> fp32 partial logits --
// v2: 128-token x 256-expert block tile, 8 waves of 64x64 (halves LDS
// bytes/MFMA vs 32x32), triple-buffered LDS with depth-2 global_load_lds
// prefetch and counted-vmcnt raw barriers (no vmcnt(0) drain in main loop).
// grid 256 = 128 token-groups x 2 K-halves; K-half pinned per-XCD (bid&7).
// LDS 144 KB: 3 buffers x (A hi 8K | A lo 8K | B hi 16K | B lo 16K).
__global__ __launch_bounds__(512, 2) void moe_main(
    const float* __restrict__ x, const char* __restrict__ khi,
    const char* __restrict__ klo, float* __restrict__ logits, int T)
{
    __shared__ __align__(16) char smem[3 * BUFSZ];

    const int tid  = threadIdx.x;
    const int w    = tid >> 6;
    const int l    = tid & 63;
    const int l31  = l & 31;
    const int half = l >> 5;
    const int mg   = w & 1;          // row group: rows mg*64..
    const int ng   = w >> 1;         // col group: cols ng*64..
    const int bid  = blockIdx.x;
    const int xcd  = bid & 7;
    const int kh   = xcd >> 2;
    const int tg   = ((bid >> 3) << 2) | (xcd & 3);
    const long t0  = (long)tg * 128;
    const int cg0  = kh * NCH;

    // staging roles: thread -> (row 0..127, 8 floats at k = au*8)
    const int arow = tid >> 2;
    const int au   = tid & 3;
    const int t16  = tid << 4;
    const int adst = au * 2048 + arow * 16;   // A image [u(4)][row(128)][16B]
    const float* xp = x + (t0 + arow) * HDIM + (long)kh * KHALF + au * 8;

    const int mgl = (mg * 64 + l31) * 16;
    const int ngl = (ng * 64 + l31) * 16;

    f32x16 accm[2][2], accc[2][2];
#pragma unroll
    for (int i = 0; i < 2; ++i)
#pragma unroll
        for (int j = 0; j < 2; ++j)
#pragma unroll
            for (int r = 0; r < 16; ++r) { accm[i][j][r] = 0.f; accc[i][j][r] = 0.f; }

    char* cur = smem;
    char* nxt = smem + BUFSZ;
    char* fut = smem + 2 * BUFSZ;

    // ---- prologue: x(0) regs; B(0)->cur, B(1)->nxt; A(0)->cur; x(1) regs ----
    float4 xa = *(const float4*)xp;
    float4 xb = *(const float4*)(xp + 4);
    {
        const long cb0 = (long)cg0 * 16384;
        gload_lds16(khi + cb0 + t16,        cur + 16384 + t16);
        gload_lds16(khi + cb0 + 8192 + t16, cur + 24576 + t16);
        gload_lds16(klo + cb0 + t16,        cur + 32768 + t16);
        gload_lds16(klo + cb0 + 8192 + t16, cur + 40960 + t16);
        const long cb1 = cb0 + 16384;
        gload_lds16(khi + cb1 + t16,        nxt + 16384 + t16);
        gload_lds16(khi + cb1 + 8192 + t16, nxt + 24576 + t16);
        gload_lds16(klo + cb1 + t16,        nxt + 32768 + t16);
        gload_lds16(klo + cb1 + 8192 + t16, nxt + 40960 + t16);
    }
    {
        f16x8 h8, l8;
        cvt8(xa, xb, h8, l8);
        *(f16x8*)(cur + adst)        = h8;
        *(f16x8*)(cur + 8192 + adst) = l8;
    }
    xa = *(const float4*)(xp + BK);
    xb = *(const float4*)(xp + BK + 4);
    // drain B(0) (oldest 4); keep B(1)+x(1) in flight
    asm volatile("s_waitcnt vmcnt(6) lgkmcnt(0)\n\ts_barrier" ::: "memory");

    for (int c = 0; c < NCH; ++c) {
        // stage A(c+1) from regs into nxt; issue x(c+2) loads
        if (c + 1 < NCH) {
            f16x8 h8, l8;
            cvt8(xa, xb, h8, l8);
            *(f16x8*)(nxt + adst)        = h8;
            *(f16x8*)(nxt + 8192 + adst) = l8;
            if (c + 2 < NCH) {
                const float* xs = xp + (long)(c + 2) * BK;
                xa = *(const float4*)xs;
                xb = *(const float4*)(xs + 4);
            }
        }
        // issue B(c+2) DMA into fut (stays in flight across the barrier)
        if (c + 2 < NCH) {
            const long cb = (long)(cg0 + c + 2) * 16384;
            gload_lds16(khi + cb + t16,        fut + 16384 + t16);
            gload_lds16(khi + cb + 8192 + t16, fut + 24576 + t16);
            gload_lds16(klo + cb + t16,        fut + 32768 + t16);
            gload_lds16(klo + cb + 8192 + t16, fut + 40960 + t16);
        }
        // compute chunk c from cur
#pragma unroll
        for (int ks = 0; ks < 2; ++ks) {
            const int u = 2 * ks + half;
            const char* Ab = cur + u * 2048;
            const char* Bb = cur + 16384 + u * 4096;
            f16x8 ah[2], al[2], bh[2], bl[2];
#pragma unroll
            for (int q = 0; q < 2; ++q) {
                ah[q] = *(const f16x8*)(Ab + mgl + q * 512);
                al[q] = *(const f16x8*)(Ab + 8192 + mgl + q * 512);
                bh[q] = *(const f16x8*)(Bb + ngl + q * 512);
                bl[q] = *(const f16x8*)(Bb + 16384 + ngl + q * 512);
            }
            __builtin_amdgcn_s_setprio(1);
#pragma unroll
            for (int rs = 0; rs < 2; ++rs)
#pragma unroll
                for (int cs = 0; cs < 2; ++cs) {
                    accm[rs][cs] = __builtin_amdgcn_mfma_f32_32x32x16_f16(ah[rs], bh[cs], accm[rs][cs], 0, 0, 0);
                    accc[rs][cs] = __builtin_amdgcn_mfma_f32_32x32x16_f16(ah[rs], bl[cs], accc[rs][cs], 0, 0, 0);
                    accc[rs][cs] = __builtin_amdgcn_mfma_f32_32x32x16_f16(al[rs], bh[cs], accc[rs][cs], 0, 0, 0);
                }
            __builtin_amdgcn_s_setprio(0);
        }
        // barrier: drain only B(c+1) (oldest); B(c+2)+x(c+2) stay in flight
        if (c + 2 < NCH) {
            asm volatile("s_waitcnt vmcnt(6) lgkmcnt(0)\n\ts_barrier" ::: "memory");
        } else if (c + 1 < NCH) {
            asm volatile("s_waitcnt vmcnt(0) lgkmcnt(0)\n\ts_barrier" ::: "memory");
        }
        char* tp = cur; cur = nxt; nxt = fut; fut = tp;
    }

    // epilogue (C layout: col=lane&31, row=(r&3)+8*(r>>2)+4*half per subtile)
    float* lg = logits + (long)kh * T * NEXP;
    const long trow = t0 + mg * 64;
    const int  col0 = ng * 64 + l31;
#pragma unroll
    for (int rs = 0; rs < 2; ++rs)
#pragma unroll
        for (int cs = 0; cs < 2; ++cs)
#pragma unroll
            for (int r = 0; r < 16; ++r) {
                const int lrow = (r & 3) + 8 * (r >> 2) + 4 * half;
                const long tok = trow + rs * 32 + lrow;
                lg[tok * NEXP + col0 + cs * 32] =
                    (float)((double)accm[rs][cs][r] + (double)accc[rs][cs][r] * (1.0 / 2048.0));
            }
}

// ---------------- gate: reduce halves, sigmoid+bias, grouped top-k, flags ---
__global__ __launch_bounds__(256) void moe_gate(
    const float* __restrict__ logits, const float* __restrict__ bias,
    float* __restrict__ out, int* __restrict__ cnt, int* __restrict__ list, int T)
{
    __shared__ float sc[64 * 257];
    const int e  = threadIdx.x;
    const long t0 = (long)blockIdx.x * 64;
    const float b = bias[e];
    const float* l0 = logits + t0 * NEXP + e;
    const float* l1 = logits + (long)T * NEXP + t0 * NEXP + e;
    for (int tt = 0; tt < 64; ++tt) {
        float lg = l0[tt * NEXP] + l1[tt * NEXP];
        sc[tt * 257 + e] = 1.0f / (1.0f + expf(-lg)) + b;
    }
    __syncthreads();

    if (e < 64) {
        float* row = sc + e * 257;

        float gsum[NGROUP];
#pragma unroll
        for (int g = 0; g < NGROUP; ++g) {
            float m1 = -1e30f, m2 = -1e30f;
            for (int j = 0; j < EPG; ++j) {
                float v = row[g * EPG + j];
                if (v > m1) { m2 = m1; m1 = v; }
                else if (v > m2) { m2 = v; }
            }
            gsum[g] = m1 + m2;
        }

        bool gsel[NGROUP];
#pragma unroll
        for (int g = 0; g < NGROUP; ++g) gsel[g] = false;
        float g4 = 0.0f;
        for (int r = 0; r < TOPKG; ++r) {
            float best = -1e30f; int bi = 0;
            for (int g = 0; g < NGROUP; ++g)
                if (!gsel[g] && gsum[g] > best) { best = gsum[g]; bi = g; }
            gsel[bi] = true; g4 = best;
        }
        float g5 = -1e30f;
        for (int g = 0; g < NGROUP; ++g)
            if (!gsel[g] && gsum[g] > g5) g5 = gsum[g];
        const float margin_g = g4 - g5;

        for (int e2 = 0; e2 < NEXP; ++e2)
            if (!gsel[e2 >> 5]) row[e2] = 0.0f;

        int   id[TOPK];
        float wv[TOPK];
        float wsum = 0.0f;
        for (int r = 0; r < TOPK; ++r) {
            float best = -1e30f; int bi = 0;
            for (int e2 = 0; e2 < NEXP; ++e2) {
                float v = row[e2];
                if (v > best) { best = v; bi = e2; }
            }
            row[bi] = -1e30f;
            id[r] = bi; wv[r] = best; wsum += best;
        }
        float s9 = -1e30f;
        for (int e2 = 0; e2 < NEXP; ++e2)
            if (row[e2] > s9) s9 = row[e2];

        float mmin = wv[TOPK - 1] - s9;
#pragma unroll
        for (int r = 0; r < TOPK - 1; ++r) {
            float d = wv[r] - wv[r + 1];
            if (d < mmin) mmin = d;
        }

        const float inv = 2.5f / (wsum + 1e-20f);
        const long base  = (t0 + e) * TOPK;
        const long wbase = (long)T * TOPK + base;
#pragma unroll
        for (int r = 0; r < TOPK; ++r) {
            out[base + r]  = (float)id[r];
            out[wbase + r] = wv[r] * inv;
        }

        if (mmin < TAU || margin_g < TAUG) {
            int p2 = atomicAdd(cnt, 1);
            if (p2 < T) list[p2] = (int)(t0 + e);
        }
    }
}

// ---------------- shared f64 selection ----------------
__device__ void select_f64(double* sd, int t, float* out, int T) {
    double gsum[NGROUP];
    for (int g = 0; g < NGROUP; ++g) {
        double m1 = -1e300, m2 = -1e300;
        for (int j = 0; j < EPG; ++j) {
            double v = sd[g * EPG + j];
            if (v > m1) { m2 = m1; m1 = v; }
            else if (v > m2) { m2 = v; }
        }
        gsum[g] = m1 + m2;
    }
    bool gsel[NGROUP];
    for (int g = 0; g < NGROUP; ++g) gsel[g] = false;
    for (int r = 0; r < TOPKG; ++r) {
        double best = -1e300; int bi = 0;
        for (int g = 0; g < NGROUP; ++g)
            if (!gsel[g] && gsum[g] > best) { best = gsum[g]; bi = g; }
        gsel[bi] = true;
    }
    for (int e2 = 0; e2 < NEXP; ++e2)
        if (!gsel[e2 >> 5]) sd[e2] = 0.0;

    int id[TOPK]; double wv[TOPK]; double wsum = 0.0;
    for (int r = 0; r < TOPK; ++r) {
        double best = -1e300; int bi = 0;
        for (int e2 = 0; e2 < NEXP; ++e2) {
            double v = sd[e2];
            if (v > best) { best = v; bi = e2; }
        }
        sd[bi] = -1e300;
        id[r] = bi; wv[r] = best; wsum += best;
    }
    const double inv = RSF / (wsum + 1e-20);
    const long base  = (long)t * TOPK;
    const long wbase = (long)T * TOPK + base;
    for (int r = 0; r < TOPK; ++r) {
        out[base + r]  = (float)id[r];
        out[wbase + r] = (float)(wv[r] * inv);
    }
}

// ---------------- refine stage A: fp64 partials, wk read ~once --------------
__global__ __launch_bounds__(256) void moe_refineA(
    const float* __restrict__ x, const float* __restrict__ wk,
    double* __restrict__ pref, const int* __restrict__ cnt,
    const int* __restrict__ list, int T)
{
    __shared__ float xb[8][224];
    int n = *cnt; if (n > T) n = T;
    int nb = n < NB_REF ? n : NB_REF;
    const int kc = blockIdx.x >> 3;
    const int tg = blockIdx.x & 7;
    const int e  = threadIdx.x;

    for (int jb = tg; jb < nb; jb += 64) {
        for (int i = 0; i < 8; ++i) {
            int j = jb + 8 * i;
            if (j >= nb) break;
            if (e < 56) {
                const float* xp = x + (long)list[j] * HDIM + kc * 224 + e * 4;
                *(float4*)&xb[i][e * 4] = *(const float4*)xp;
            }
        }
        __syncthreads();

        double acc[8];
#pragma unroll
        for (int i = 0; i < 8; ++i) acc[i] = 0.0;
        const float* wp = wk + (long)(kc * 224) * NEXP + e;
#pragma unroll 4
        for (int k = 0; k < 224; ++k) {
            double wv = (double)wp[(long)k * NEXP];
#pragma unroll
            for (int i = 0; i < 8; ++i)
                acc[i] = fma((double)xb[i][k], wv, acc[i]);
        }
        for (int i = 0; i < 8; ++i) {
            int j = jb + 8 * i;
            if (j < nb) pref[((long)j * 32 + kc) * NEXP + e] = acc[i];
        }
        __syncthreads();
    }
}

// ---------------- refine stage B: reduce + exact select ---------------------
__global__ __launch_bounds__(256) void moe_refineB(
    const float* __restrict__ x, const float* __restrict__ wk,
    const float* __restrict__ bias, float* __restrict__ out,
    const double* __restrict__ pref, const int* __restrict__ cnt,
    const int* __restrict__ list, int T)
{
    __shared__ double sd[NEXP];
    int n = *cnt; if (n > T) n = T;
    int nb = n < NB_REF ? n : NB_REF;
    const int e = threadIdx.x;
    const int i = blockIdx.x;

    const int t = (i < nb) ? list[i] : -1;
    double s = 0.0;
    if (t >= 0) {
        const double* pp = pref + (long)i * 32 * NEXP + e;
#pragma unroll
        for (int kc = 0; kc < 32; ++kc) s += pp[kc * NEXP];
    }
    sd[e] = (t >= 0) ? (1.0 / (1.0 + exp(-s)) + (double)bias[e]) : 0.0;
    __syncthreads();
    if (t >= 0 && e == 0) select_f64(sd, t, out, T);
    __syncthreads();

    // overflow fallback (n > NB_REF): slow exact per-token — expected never
    for (int j = NB_REF + i; j < n; j += 512) {
        const int tt = list[j];
        const float* xr = x + (long)tt * HDIM;
        double a0 = 0.0, a1 = 0.0;
        for (int k = 0; k < HDIM; k += 2) {
            a0 = fma((double)xr[k],     (double)wk[(long)k * NEXP + e],       a0);
            a1 = fma((double)xr[k + 1], (double)wk[(long)(k + 1) * NEXP + e], a1);
        }
        sd[e] = 1.0 / (1.0 + exp(-(a0 + a1))) + (double)bias[e];
        __syncthreads();
        if (e == 0) select_f64(sd, tt, out, T);
        __syncthreads();
    }
}

// ---------------- fallback: full fp64 (used only if ws too small) -----------
__global__ __launch_bounds__(256) void moe_gate_f64_full(
    const float* __restrict__ x, const float* __restrict__ wk,
    const float* __restrict__ bias, float* __restrict__ out, int T)
{
    __shared__ double sc[16][NEXP + 1];
    const int  e  = threadIdx.x;
    const long t0 = (long)blockIdx.x * 16;
    const float* xb = x + t0 * HDIM;
    double acc[16];
#pragma unroll
    for (int t = 0; t < 16; ++t) acc[t] = 0.0;
    for (int k = 0; k < HDIM; k += 4) {
        double kv0 = (double)wk[(long)(k + 0) * NEXP + e];
        double kv1 = (double)wk[(long)(k + 1) * NEXP + e];
        double kv2 = (double)wk[(long)(k + 2) * NEXP + e];
        double kv3 = (double)wk[(long)(k + 3) * NEXP + e];
#pragma unroll
        for (int t = 0; t < 16; ++t) {
            const float* xr = xb + (long)t * HDIM + k;
            double a = acc[t];
            a = fma((double)xr[0], kv0, a);
            a = fma((double)xr[1], kv1, a);
            a = fma((double)xr[2], kv2, a);
            a = fma((double)xr[3], kv3, a);
            acc[t] = a;
        }
    }
    const double b = (double)bias[e];
#pragma unroll
    for (int t = 0; t < 16; ++t)
        sc[t][e] = 1.0 / (1.0 + exp(-acc[t])) + b;
    __syncthreads();
    if (e < 16) select_f64(&sc[e][0], (int)(t0 + e), out, T);
}

extern "C" void kernel_launch(void* const* d_in, const int* in_sizes, int n_in,
                              void* d_out, int out_size, void* d_ws, size_t ws_size,
                              hipStream_t stream) {
    const float* x    = (const float*)d_in[0];
    const float* wk   = (const float*)d_in[1];
    const float* bias = (const float*)d_in[2];
    float* out = (float*)d_out;
    const int T = in_sizes[0] / HDIM;    // 16384

    if (ws_size < WS_NEED) {   // safety net: exact fp64, no workspace needed
        hipLaunchKernelGGL(moe_gate_f64_full, dim3(T / 16), dim3(256), 0, stream,
                           x, wk, bias, out, T);
        return;
    }

    char*   ws     = (char*)d_ws;
    int*    cnt    = (int*)(ws + WS_CNT_OFF);
    int*    list   = (int*)(ws + WS_LIST_OFF);
    char*   khi    = ws + WS_KHI_OFF;
    char*   klo    = ws + WS_KLO_OFF;
    float*  logits = (float*)(ws + WS_BUF_OFF);
    double* pref   = (double*)(ws + WS_BUF_OFF);  // aliased after gate reads

    hipLaunchKernelGGL(moe_prep,    dim3(224), dim3(256),  0, stream, wk, khi, klo, cnt);
    hipLaunchKernelGGL(moe_main,    dim3((T / 128) * 2), dim3(512), 0, stream, x, khi, klo, logits, T);
    hipLaunchKernelGGL(moe_gate,    dim3(T / 64), dim3(256), 0, stream, logits, bias, out, cnt, list, T);
    hipLaunchKernelGGL(moe_refineA, dim3(256), dim3(256),  0, stream, x, wk, pref, cnt, list, T);
    hipLaunchKernelGGL(moe_refineB, dim3(512), dim3(256),  0, stream, x, wk, bias, out, pref, cnt, list, T);
}